// Round 7
// baseline (227.989 us; speedup 1.0000x reference)
//
#include <hip/hip_runtime.h>
#include <hip/hip_bf16.h>
#include <math.h>

// DecoderSphere B=16,T=65536,D=32. MFMA bf16 + bpermute layout transform.
// R7 = R5 single-tile main loop + R6 LDS-staged weight preamble +
//      v_cvt_pk_bf16_f32 hardware pack (guarded; falls back to bit-trick RNE).
// launch_bounds(256,2): (256,4) spilled the 80-VGPR wf array in R4. Keep.

typedef __attribute__((ext_vector_type(8))) short short8;
typedef __attribute__((ext_vector_type(4))) float f32x4;

#define CFW 36    // cf row stride (dwords)
#define WTS 40    // staged W^T col stride (bf16 units): 80 B, 16 B-aligned frags

#if __has_builtin(__builtin_amdgcn_cvt_pk_bf16_f32)
typedef __attribute__((ext_vector_type(2))) __bf16 bf16x2_t;
static __device__ __forceinline__ unsigned pk2(float a, float b) {
    // dst.lo = bf16(a), dst.hi = bf16(b), RNE — 1 VALU op
    return __builtin_bit_cast(unsigned, __builtin_amdgcn_cvt_pk_bf16_f32(a, b));
}
#else
// pack 2 floats to bf16x2, RNE (== __float2bfloat16 for finite values)
static __device__ __forceinline__ unsigned pk2(float a, float b) {
    unsigned ua = __builtin_bit_cast(unsigned, a);
    unsigned ub = __builtin_bit_cast(unsigned, b);
    ua += 0x7fffu + ((ua >> 16) & 1u);
    ub += 0x7fffu + ((ub >> 16) & 1u);
    return __builtin_amdgcn_perm(ub, ua, 0x07060302);  // {lo=hi16(ua), hi=hi16(ub)}
}
#endif

// C-layout (x0=feats 16*0+4q+r, x1=feats 16*1+4q+r of pt m15) -> relu -> bf16
// -> B-frag (k=8q+j feats of pt m15). Pure intra-column redistribution.
static __device__ __forceinline__ short8 xform(const f32x4 x0, const f32x4 x1,
                                               int a01, int a23, bool hs) {
    const int p00 = (int)pk2(fmaxf(x0[0], 0.f), fmaxf(x0[1], 0.f));
    const int p01 = (int)pk2(fmaxf(x0[2], 0.f), fmaxf(x0[3], 0.f));
    const int p10 = (int)pk2(fmaxf(x1[0], 0.f), fmaxf(x1[1], 0.f));
    const int p11 = (int)pk2(fmaxf(x1[2], 0.f), fmaxf(x1[3], 0.f));
    const int s0a = __builtin_amdgcn_ds_bpermute(a01, p00);
    const int s0b = __builtin_amdgcn_ds_bpermute(a01, p10);
    const int s1a = __builtin_amdgcn_ds_bpermute(a01, p01);
    const int s1b = __builtin_amdgcn_ds_bpermute(a01, p11);
    const int s2a = __builtin_amdgcn_ds_bpermute(a23, p00);
    const int s2b = __builtin_amdgcn_ds_bpermute(a23, p10);
    const int s3a = __builtin_amdgcn_ds_bpermute(a23, p01);
    const int s3b = __builtin_amdgcn_ds_bpermute(a23, p11);
    int4 r;
    r.x = hs ? s0b : s0a;
    r.y = hs ? s1b : s1a;
    r.z = hs ? s2b : s2a;
    r.w = hs ? s3b : s3a;
    return __builtin_bit_cast(short8, r);
}

__global__ __launch_bounds__(256, 2) void decoder_mfma(
    const float* __restrict__ p,
    const float* __restrict__ c,
    const float* __restrict__ fc_p_w,
    const float* __restrict__ fc_p_b,
    const float* __restrict__ w0g,
    const float* __restrict__ b0g,
    const float* __restrict__ w1g,
    const float* __restrict__ b1g,
    const float* __restrict__ fc_out_w,
    const float* __restrict__ fc_out_b,
    float* __restrict__ out)
{
    __shared__ float lds[9728];   // 38912 B
    const int tid  = threadIdx.x;
    const int wave = tid >> 6;
    const int lane = tid & 63;
    const int m15  = lane & 15;
    const int q    = lane >> 4;

    float* cfb = lds + wave * 2304;   // [64 pts][CFW] f32 cf (after weight phase)
    float* cb  = lds + 9216;          // constants [512]

    // ---- stage constants ----
    // [0,96): fc_p_w [96,128): fc_p_b [128,288): b0 [288,448): b1
    // [448,480): fc_out_w [480]: fc_out_b
    for (int t = tid; t < 481; t += 256) {
        float v;
        if      (t < 96)  v = fc_p_w[t];
        else if (t < 128) v = fc_p_b[t - 96];
        else if (t < 288) v = b0g[t - 128];
        else if (t < 448) v = b1g[t - 288];
        else if (t < 480) v = fc_out_w[t - 448];
        else              v = fc_out_b[0];
        cb[t] = v;
    }

    // ---- stage W^T (bf16) into LDS: 10 matrices x [32 cols][WTS] ----
    // matrix m<5: w0 layer m; m>=5: w1 layer m-5. element (k,c) -> wt[m][c][k].
    {
        unsigned short* wt = (unsigned short*)lds;
        const int ccol = tid & 31;          // column (output feature)
        const int kg   = (tid >> 5) * 4;    // 4 consecutive k rows
#pragma unroll
        for (int m = 0; m < 10; ++m) {
            const float* src = (m < 5) ? (w0g + m * 1024) : (w1g + (m - 5) * 1024);
            const float e0 = src[(kg + 0) * 32 + ccol];
            const float e1 = src[(kg + 1) * 32 + ccol];
            const float e2 = src[(kg + 2) * 32 + ccol];
            const float e3 = src[(kg + 3) * 32 + ccol];
            unsigned* dst = (unsigned*)(wt + m * (32 * WTS) + ccol * WTS + kg);
            dst[0] = pk2(e0, e1);
            dst[1] = pk2(e2, e3);
        }
    }
    __syncthreads();

    // ---- fill A-frags: wf[i][mat][h], A[m=lane&15][k=8q+j] = W[k][16h+m] ----
    short8 wf[5][2][2];
    {
        const unsigned short* wt = (const unsigned short*)lds;
#pragma unroll
        for (int i = 0; i < 5; ++i) {
#pragma unroll
            for (int h = 0; h < 2; ++h) {
                const int co = (16 * h + m15) * WTS + 8 * q;
                wf[i][0][h] = *(const short8*)(wt + i * (32 * WTS) + co);
                wf[i][1][h] = *(const short8*)(wt + (5 + i) * (32 * WTS) + co);
            }
        }
    }
    __syncthreads();   // all frag reads done before cf overwrites the region

    // ================= phase 1: per-lane interp =================
    const float PI_F = 3.1415927410125732f;
    const int g = blockIdx.x * 256 + tid;
    const int b = g >> 16;                      // T = 65536

    const float px = p[3 * g + 0];
    const float py = p[3 * g + 1];
    const float pz = p[3 * g + 2];

    const float lat = 90.0f - (atan2f(pz, sqrtf(px * px + py * py)) * 180.0f) / PI_F;
    const float mer = fmodf(360.0f + (atan2f(py, px) * 180.0f) / PI_F, 360.0f);

    const int xg = (int)floorf(mer / 5.625f);
    const int yg = (int)floorf(lat / 2.8125f);

    const int xl = (xg + 63) & 63;
    const int xr = (xg + 1) & 63;
    const int ylo = yg - 1 - ((yg - 1) >> 6);
    const int yhi = yg + 1 - ((yg + 1) >> 6);

    const float dx = (float)(xr - xg);
    const float dy = (float)(yhi - yg);

    const int yloi = ylo < 63 ? ylo : 63;
    const int yhii = yhi < 63 ? yhi : 63;

    const float w11 = dx * dy;
    const float w12 = (1.0f - dx) * dy;
    const float w21 = dx * (1.0f - dy);
    const float w22 = (1.0f - dx) * (1.0f - dy);

    const float* gb  = c + (size_t)b * (64 * 64 * 32);
    const float* r11 = gb + (xl * 64 + yloi) * 32;
    const float* r12 = gb + (xr * 64 + yloi) * 32;
    const float* r21 = gb + (xl * 64 + yhii) * 32;
    const float* r22 = gb + (xr * 64 + yhii) * 32;

    float* cfr = cfb + lane * CFW;
#pragma unroll
    for (int d = 0; d < 32; d += 4) {
        const f32x4 a  = *(const f32x4*)(r11 + d);
        const f32x4 e  = *(const f32x4*)(r12 + d);
        const f32x4 f  = *(const f32x4*)(r21 + d);
        const f32x4 h4 = *(const f32x4*)(r22 + d);
        f32x4 v = w11 * a + w12 * e + w21 * f + w22 * h4;
        *(f32x4*)(cfr + d) = v;
    }

    __builtin_amdgcn_wave_barrier();   // order phase-1 LDS writes before reads

    // ================= phase 2: 4 tiles of 16 points =================
    const int a01 = 4 * (m15 + 32 * (q & 1));   // bperm src for slots 0,1
    const int a23 = a01 + 64;                   // slots 2,3
    const bool hs = q >= 2;

    const int ipx = __builtin_bit_cast(int, px);
    const int ipy = __builtin_bit_cast(int, py);
    const int ipz = __builtin_bit_cast(int, pz);

#pragma unroll 1
    for (int t = 0; t < 4; ++t) {
        const int ptl = t * 16 + m15;
        const int ap  = 4 * ptl;
        const float qx = __builtin_bit_cast(float, __builtin_amdgcn_ds_bpermute(ap, ipx));
        const float qy = __builtin_bit_cast(float, __builtin_amdgcn_ds_bpermute(ap, ipy));
        const float qz = __builtin_bit_cast(float, __builtin_amdgcn_ds_bpermute(ap, ipz));

        f32x4 net[2], cf[2];
#pragma unroll
        for (int h = 0; h < 2; ++h) {
            const int fo = 16 * h + 4 * q;
            const f32x4 wx = *(const f32x4*)(cb + fo);
            const f32x4 wy = *(const f32x4*)(cb + 32 + fo);
            const f32x4 wz = *(const f32x4*)(cb + 64 + fo);
            const f32x4 bb = *(const f32x4*)(cb + 96 + fo);
            net[h] = qx * wx + qy * wy + qz * wz + bb;
            cf[h]  = *(const f32x4*)(cfb + ptl * CFW + fo);
        }

#pragma unroll
        for (int i = 0; i < 5; ++i) {
            net[0] += cf[0];
            net[1] += cf[1];

            const short8 xf = xform(net[0], net[1], a01, a23, hs);

            const int b0o = 128 + i * 32 + 4 * q;
            const f32x4 h0 = __builtin_amdgcn_mfma_f32_16x16x32_bf16(
                wf[i][0][0], xf, *(const f32x4*)(cb + b0o), 0, 0, 0);
            const f32x4 h1 = __builtin_amdgcn_mfma_f32_16x16x32_bf16(
                wf[i][0][1], xf, *(const f32x4*)(cb + b0o + 16), 0, 0, 0);

            const short8 hf = xform(h0, h1, a01, a23, hs);

            net[0] = __builtin_amdgcn_mfma_f32_16x16x32_bf16(wf[i][1][0], hf, net[0], 0, 0, 0);
            net[1] = __builtin_amdgcn_mfma_f32_16x16x32_bf16(wf[i][1][1], hf, net[1], 0, 0, 0);

            const int b1o = 288 + i * 32 + 4 * q;
            net[0] += *(const f32x4*)(cb + b1o);
            net[1] += *(const f32x4*)(cb + b1o + 16);
        }

        // epilogue: out[pt] = sum_f relu(net[f][pt]) * ow[f] + ob
        const f32x4 ow0 = *(const f32x4*)(cb + 448 + 4 * q);
        const f32x4 ow1 = *(const f32x4*)(cb + 448 + 16 + 4 * q);
        float s = 0.f;
#pragma unroll
        for (int r = 0; r < 4; ++r)
            s += fmaxf(net[0][r], 0.f) * ow0[r] + fmaxf(net[1][r], 0.f) * ow1[r];
        s += __shfl_xor(s, 16, 64);
        s += __shfl_xor(s, 32, 64);
        if (q == 0)
            out[blockIdx.x * 256 + wave * 64 + ptl] = s + cb[480];
    }
}

extern "C" void kernel_launch(void* const* d_in, const int* in_sizes, int n_in,
                              void* d_out, int out_size, void* d_ws, size_t ws_size,
                              hipStream_t stream) {
    const float* p        = (const float*)d_in[0];
    const float* c        = (const float*)d_in[2];
    const float* fc_p_w   = (const float*)d_in[4];
    const float* fc_p_b   = (const float*)d_in[5];
    const float* w0       = (const float*)d_in[6];
    const float* b0       = (const float*)d_in[7];
    const float* w1       = (const float*)d_in[8];
    const float* b1       = (const float*)d_in[9];
    const float* fc_out_w = (const float*)d_in[10];
    const float* fc_out_b = (const float*)d_in[11];
    float* out = (float*)d_out;

    dim3 block(256);
    dim3 grid((16 * 65536) / 256);   // 4096 blocks
    hipLaunchKernelGGL(decoder_mfma, grid, block, 0, stream,
                       p, c, fc_p_w, fc_p_b, w0, b0, w1, b1,
                       fc_out_w, fc_out_b, out);
}

// Round 8
// 211.120 us; speedup vs baseline: 1.0799x; 1.0799x over previous
//
#include <hip/hip_runtime.h>
#include <hip/hip_bf16.h>
#include <math.h>

// DecoderSphere B=16,T=65536,D=32. MFMA bf16, PERMUTED-WEIGHT layout.
// Key idea (R8): A-row order is free, so stage W^T with rows permuted by
//   sigma_h(m) = 8*(m>>2) + 4h + (m&3)
// so that the MFMA C-output reg (h,q,r) holds feat 8q+4h+r of pt m15.
// Then lane(m15,q) holds exactly feats 8q..8q+7 of its point — the B-fragment
// of the NEXT matmul — so the inter-matmul transform is just relu+pack
// (8 fmax + 4 cvt_pk), ZERO bpermute/cndmask. All bias/cf/fc reads use
// shifted-contiguous b128 offsets.
// Grid 1024 x 4 groups: weight preamble amortized 4x, exactly 4 blocks/CU.
// launch_bounds(256,2): (256,4) spilled the 80-VGPR wf array in R4. Keep.

typedef __attribute__((ext_vector_type(8))) short short8;
typedef __attribute__((ext_vector_type(4))) float f32x4;

#define CFW 36    // cf row stride (dwords)
#define WTS 40    // staged W^T col stride (bf16 units): 80 B, 16 B-aligned frags

#if __has_builtin(__builtin_amdgcn_cvt_pk_bf16_f32)
static __device__ __forceinline__ unsigned pk2(float a, float b) {
    return __builtin_bit_cast(unsigned, __builtin_amdgcn_cvt_pk_bf16_f32(a, b));
}
#else
// pack 2 floats to bf16x2, RNE (== __float2bfloat16 for finite values)
static __device__ __forceinline__ unsigned pk2(float a, float b) {
    unsigned ua = __builtin_bit_cast(unsigned, a);
    unsigned ub = __builtin_bit_cast(unsigned, b);
    ua += 0x7fffu + ((ua >> 16) & 1u);
    ub += 0x7fffu + ((ub >> 16) & 1u);
    return __builtin_amdgcn_perm(ub, ua, 0x07060302);
}
#endif

// relu + pack C-accumulators (permuted layout) into the next B-fragment:
// x0 = feats 8q+0..3, x1 = feats 8q+4..7 of pt m15 -> B[k=8q+j][n=m15]
static __device__ __forceinline__ short8 relu_pack(const f32x4 x0, const f32x4 x1) {
    int4 r;
    r.x = (int)pk2(fmaxf(x0[0], 0.f), fmaxf(x0[1], 0.f));
    r.y = (int)pk2(fmaxf(x0[2], 0.f), fmaxf(x0[3], 0.f));
    r.z = (int)pk2(fmaxf(x1[0], 0.f), fmaxf(x1[1], 0.f));
    r.w = (int)pk2(fmaxf(x1[2], 0.f), fmaxf(x1[3], 0.f));
    return __builtin_bit_cast(short8, r);
}

__global__ __launch_bounds__(256, 2) void decoder_mfma(
    const float* __restrict__ p,
    const float* __restrict__ c,
    const float* __restrict__ fc_p_w,
    const float* __restrict__ fc_p_b,
    const float* __restrict__ w0g,
    const float* __restrict__ b0g,
    const float* __restrict__ w1g,
    const float* __restrict__ b1g,
    const float* __restrict__ fc_out_w,
    const float* __restrict__ fc_out_b,
    float* __restrict__ out)
{
    __shared__ float lds[9728];   // 38912 B
    const int tid  = threadIdx.x;
    const int wave = tid >> 6;
    const int lane = tid & 63;
    const int m15  = lane & 15;
    const int q    = lane >> 4;

    float* cfb = lds + wave * 2304;   // [64 pts][CFW] f32 cf (after weight phase)
    float* cb  = lds + 9216;          // constants [512]

    // ---- stage constants ----
    // [0,96): fc_p_w [96,128): fc_p_b [128,288): b0 [288,448): b1
    // [448,480): fc_out_w [480]: fc_out_b
    for (int t = tid; t < 481; t += 256) {
        float v;
        if      (t < 96)  v = fc_p_w[t];
        else if (t < 128) v = fc_p_b[t - 96];
        else if (t < 288) v = b0g[t - 128];
        else if (t < 448) v = b1g[t - 288];
        else if (t < 480) v = fc_out_w[t - 448];
        else              v = fc_out_b[0];
        cb[t] = v;
    }

    // ---- stage W^T (bf16, sigma-permuted cols) into LDS ----
    // wt[m][cslot][k]: cslot = 16h+mm holds W[k][sigma] with
    // sigma = 8*(mm>>2) + 4h + (mm&3).
    {
        unsigned short* wt = (unsigned short*)lds;
        const int ccol = tid & 31;
        const int kg   = (tid >> 5) * 4;
        const int cm   = ccol & 15, ch = ccol >> 4;
        const int scol = 8 * (cm >> 2) + 4 * ch + (cm & 3);
#pragma unroll
        for (int m = 0; m < 10; ++m) {
            const float* src = (m < 5) ? (w0g + m * 1024) : (w1g + (m - 5) * 1024);
            const float e0 = src[(kg + 0) * 32 + scol];
            const float e1 = src[(kg + 1) * 32 + scol];
            const float e2 = src[(kg + 2) * 32 + scol];
            const float e3 = src[(kg + 3) * 32 + scol];
            unsigned* dst = (unsigned*)(wt + m * (32 * WTS) + ccol * WTS + kg);
            dst[0] = pk2(e0, e1);
            dst[1] = pk2(e2, e3);
        }
    }
    __syncthreads();

    // ---- fill A-frags: A[m=lane&15][k=8q+j] = W[k][sigma_h(m)] ----
    short8 wf[5][2][2];
    {
        const unsigned short* wt = (const unsigned short*)lds;
#pragma unroll
        for (int i = 0; i < 5; ++i) {
#pragma unroll
            for (int h = 0; h < 2; ++h) {
                const int co = (16 * h + m15) * WTS + 8 * q;
                wf[i][0][h] = *(const short8*)(wt + i * (32 * WTS) + co);
                wf[i][1][h] = *(const short8*)(wt + (5 + i) * (32 * WTS) + co);
            }
        }
    }
    __syncthreads();   // frag reads done before cf overwrites the region

    const float PI_F = 3.1415927410125732f;
    const int gbase = blockIdx.x * 1024;

#pragma unroll 1
    for (int grp = 0; grp < 4; ++grp) {
        // ============== phase 1: per-lane interp (256 pts/block) ==============
        const int g = gbase + grp * 256 + tid;
        const int b = g >> 16;                      // T = 65536

        const float px = p[3 * g + 0];
        const float py = p[3 * g + 1];
        const float pz = p[3 * g + 2];

        const float lat = 90.0f - (atan2f(pz, sqrtf(px * px + py * py)) * 180.0f) / PI_F;
        const float mer = fmodf(360.0f + (atan2f(py, px) * 180.0f) / PI_F, 360.0f);

        const int xg = (int)floorf(mer / 5.625f);
        const int yg = (int)floorf(lat / 2.8125f);

        const int xl = (xg + 63) & 63;
        const int xr = (xg + 1) & 63;
        const int ylo = yg - 1 - ((yg - 1) >> 6);
        const int yhi = yg + 1 - ((yg + 1) >> 6);

        const float dx = (float)(xr - xg);
        const float dy = (float)(yhi - yg);

        const int yloi = ylo < 63 ? ylo : 63;
        const int yhii = yhi < 63 ? yhi : 63;

        const float w11 = dx * dy;
        const float w12 = (1.0f - dx) * dy;
        const float w21 = dx * (1.0f - dy);
        const float w22 = (1.0f - dx) * (1.0f - dy);

        const float* gb  = c + (size_t)b * (64 * 64 * 32);
        const float* r11 = gb + (xl * 64 + yloi) * 32;
        const float* r12 = gb + (xr * 64 + yloi) * 32;
        const float* r21 = gb + (xl * 64 + yhii) * 32;
        const float* r22 = gb + (xr * 64 + yhii) * 32;

        float* cfr = cfb + lane * CFW;
#pragma unroll
        for (int d = 0; d < 32; d += 4) {
            const f32x4 a  = *(const f32x4*)(r11 + d);
            const f32x4 e  = *(const f32x4*)(r12 + d);
            const f32x4 f  = *(const f32x4*)(r21 + d);
            const f32x4 h4 = *(const f32x4*)(r22 + d);
            f32x4 v = w11 * a + w12 * e + w21 * f + w22 * h4;
            *(f32x4*)(cfr + d) = v;
        }

        __builtin_amdgcn_wave_barrier();   // cf writes before cf reads

        // ============== phase 2: 4 tiles of 16 points ==============
        const int ipx = __builtin_bit_cast(int, px);
        const int ipy = __builtin_bit_cast(int, py);
        const int ipz = __builtin_bit_cast(int, pz);

#pragma unroll 1
        for (int t = 0; t < 4; ++t) {
            const int ptl = t * 16 + m15;
            const int ap  = 4 * ptl;
            const float qx = __builtin_bit_cast(float, __builtin_amdgcn_ds_bpermute(ap, ipx));
            const float qy = __builtin_bit_cast(float, __builtin_amdgcn_ds_bpermute(ap, ipy));
            const float qz = __builtin_bit_cast(float, __builtin_amdgcn_ds_bpermute(ap, ipz));

            // permuted C layout: reg (h,r) = feat 8q+4h+r of pt m15
            f32x4 net[2], cf[2];
#pragma unroll
            for (int h = 0; h < 2; ++h) {
                const int fo = 8 * q + 4 * h;
                const f32x4 wx = *(const f32x4*)(cb + fo);
                const f32x4 wy = *(const f32x4*)(cb + 32 + fo);
                const f32x4 wz = *(const f32x4*)(cb + 64 + fo);
                const f32x4 bb = *(const f32x4*)(cb + 96 + fo);
                net[h] = qx * wx + qy * wy + qz * wz + bb;
                cf[h]  = *(const f32x4*)(cfb + ptl * CFW + fo);
            }

#pragma unroll
            for (int i = 0; i < 5; ++i) {
                net[0] += cf[0];
                net[1] += cf[1];

                const short8 xf = relu_pack(net[0], net[1]);

                const int b0o = 128 + i * 32 + 8 * q;
                const f32x4 h0 = __builtin_amdgcn_mfma_f32_16x16x32_bf16(
                    wf[i][0][0], xf, *(const f32x4*)(cb + b0o), 0, 0, 0);
                const f32x4 h1 = __builtin_amdgcn_mfma_f32_16x16x32_bf16(
                    wf[i][0][1], xf, *(const f32x4*)(cb + b0o + 4), 0, 0, 0);

                const short8 hf = relu_pack(h0, h1);

                net[0] = __builtin_amdgcn_mfma_f32_16x16x32_bf16(wf[i][1][0], hf, net[0], 0, 0, 0);
                net[1] = __builtin_amdgcn_mfma_f32_16x16x32_bf16(wf[i][1][1], hf, net[1], 0, 0, 0);

                const int b1o = 288 + i * 32 + 8 * q;
                net[0] += *(const f32x4*)(cb + b1o);
                net[1] += *(const f32x4*)(cb + b1o + 4);
            }

            // epilogue: lane holds feats 8q..8q+7 of pt m15
            const f32x4 ow0 = *(const f32x4*)(cb + 448 + 8 * q);
            const f32x4 ow1 = *(const f32x4*)(cb + 448 + 8 * q + 4);
            float s = 0.f;
#pragma unroll
            for (int r = 0; r < 4; ++r)
                s += fmaxf(net[0][r], 0.f) * ow0[r] + fmaxf(net[1][r], 0.f) * ow1[r];
            s += __shfl_xor(s, 16, 64);
            s += __shfl_xor(s, 32, 64);
            if (q == 0)
                out[gbase + grp * 256 + wave * 64 + ptl] = s + cb[480];
        }

        __builtin_amdgcn_wave_barrier();   // cf reads done before next group's writes
    }
}

extern "C" void kernel_launch(void* const* d_in, const int* in_sizes, int n_in,
                              void* d_out, int out_size, void* d_ws, size_t ws_size,
                              hipStream_t stream) {
    const float* p        = (const float*)d_in[0];
    const float* c        = (const float*)d_in[2];
    const float* fc_p_w   = (const float*)d_in[4];
    const float* fc_p_b   = (const float*)d_in[5];
    const float* w0       = (const float*)d_in[6];
    const float* b0       = (const float*)d_in[7];
    const float* w1       = (const float*)d_in[8];
    const float* b1       = (const float*)d_in[9];
    const float* fc_out_w = (const float*)d_in[10];
    const float* fc_out_b = (const float*)d_in[11];
    float* out = (float*)d_out;

    dim3 block(256);
    dim3 grid(1024);   // 4 groups of 256 pts per block
    hipLaunchKernelGGL(decoder_mfma, grid, block, 0, stream,
                       p, c, fc_p_w, fc_p_b, w0, b0, w1, b1,
                       fc_out_w, fc_out_b, out);
}